// Round 16
// baseline (540.045 us; speedup 1.0000x reference)
//
#include <hip/hip_runtime.h>
#include <hip/hip_bf16.h>

// BiaffineAttention on MI355X — round 16: single persistent kernel.
// r15 data: setprio null; kernel-config spread r2-r14 only +-7us around ~170
// while est. kernel sum is ~105us -> ~60us residue attributed to the 3
// inter-dispatch boundaries (drain + XCD L2 writeback + CP gap).
// r16: ONE 512-block kernel, phases {prep | GEMM1+MT | GEMM2 | GEMM3}
// separated by manual device-scope grid barriers (threadfence + atomic +
// spin). Co-residency: 48KB LDS -> >=2 blocks/CU worst case -> capacity
// >= 512 = grid (3/CU expected). Barrier counter zeroed via 4B
// hipMemsetAsync (graph-capturable). MT computed as 64 64x64-tile second
// units on blocks 0..63 (~+5us imbalance).
// GEMM bodies identical to r14: depth-2 counted-vmcnt (wait-before-barrier),
// T2 both-sides XOR swizzle (conflicts==0), XCD-bijective swizzle, bias folds.

#define HIDDEN 1024
#define ARC 500
#define AP 512
#define ROWS 8192
#define NB 512  // grid size

typedef __attribute__((ext_vector_type(4))) float f32x4;
typedef __attribute__((ext_vector_type(8))) short short8;

static __device__ __forceinline__ ushort f2bf(float f) {
  union { float f; unsigned u; } v; v.f = f;
  unsigned r = v.u + 0x7fffu + ((v.u >> 16) & 1u);  // RNE
  return (ushort)(r >> 16);
}

// Device-scope grid barrier. All blocks co-resident (grid <= capacity).
static __device__ __forceinline__ void gsync(unsigned* cnt, unsigned target) {
  __syncthreads();
  __threadfence();  // release: my phase-N writes visible device-wide
  if (threadIdx.x == 0) {
    atomicAdd(cnt, 1u);
    while (atomicAdd(cnt, 0u) < target) __builtin_amdgcn_s_sleep(2);
  }
  __syncthreads();
  __threadfence();  // acquire: don't let phase-N+1 reads move above
}

// ---- depth-2 counted-vmcnt bf16 GEMM body: C = A @ B^T (r14-identical) ----
template <int BM, int BN>
__device__ __forceinline__ void gemm_body(
    const ushort* __restrict__ A, const ushort* __restrict__ B,
    const float* __restrict__ bias, int bias_mode,  // 0 none, 1 per-col, 2 scalar
    void* __restrict__ C, int out_bf16, int relu,
    int lda, int ldb, int ldc, int K, int tm, int tn, ushort* lds) {
  constexpr int WR = BM / 2, WCC = BN / 2;
  constexpr int MFR = WR / 16, NFR = WCC / 16;
  constexpr int CA = BM / 64, CB = BN / 64;
  constexpr int LPS = CA + CB;
  constexpr int BUFSZ = (BM + BN) * 32;

  const int t = threadIdx.x;
  const int w = t >> 6;
  const int l = t & 63;
  const int wr = w >> 1, wc = w & 1;

  f32x4 acc[MFR][NFR];
#pragma unroll
  for (int m = 0; m < MFR; ++m)
#pragma unroll
    for (int n = 0; n < NFR; ++n) acc[m][n] = f32x4{0.f, 0.f, 0.f, 0.f};

  const int srow = w * 16 + (l >> 2);
  const int scol = (((l & 3) ^ ((l >> 3) & 3))) * 8;  // pre-swizzled global chunk
  const ushort* ag = A + (size_t)(tm + srow) * lda + scol;
  const ushort* bg = B + (size_t)(tn + srow) * ldb + scol;
  const int lofs = w * 512;

  const int fr = l & 15, fh = l >> 4;
  const int swz = (fr >> 1) & 3;
  const int fAo = (wr * WR + fr) * 32 + (fh ^ swz) * 8;
  const int fBo = (wc * WCC + fr) * 32 + (fh ^ swz) * 8;

  auto stage = [&](int kt, ushort* buf) {
#pragma unroll
    for (int c = 0; c < CA; ++c)
      __builtin_amdgcn_global_load_lds(
          (const __attribute__((address_space(1))) void*)(ag + (size_t)c * 64 * lda + kt),
          (__attribute__((address_space(3))) void*)(buf + lofs + c * 2048), 16, 0, 0);
#pragma unroll
    for (int c = 0; c < CB; ++c)
      __builtin_amdgcn_global_load_lds(
          (const __attribute__((address_space(1))) void*)(bg + (size_t)c * 64 * ldb + kt),
          (__attribute__((address_space(3))) void*)(buf + BM * 32 + lofs + c * 2048), 16, 0, 0);
  };
  auto compute = [&](const ushort* buf) {
    short8 af[MFR], bf[NFR];
#pragma unroll
    for (int m = 0; m < MFR; ++m) af[m] = *(const short8*)(buf + fAo + m * 16 * 32);
#pragma unroll
    for (int n = 0; n < NFR; ++n) bf[n] = *(const short8*)(buf + BM * 32 + fBo + n * 16 * 32);
#pragma unroll
    for (int m = 0; m < MFR; ++m)
#pragma unroll
      for (int n = 0; n < NFR; ++n)
        acc[m][n] = __builtin_amdgcn_mfma_f32_16x16x32_bf16(af[m], bf[n], acc[m][n], 0, 0, 0);
  };

  const int nt = K >> 5;
  stage(0, lds);
  stage(32, lds + BUFSZ);
  int cs = 0, ps = 2;
  for (int ti = 0; ti < nt; ++ti) {
    if (ti + 1 < nt) {
      if constexpr (LPS == 2)      asm volatile("s_waitcnt vmcnt(2)" ::: "memory");
      else if constexpr (LPS == 3) asm volatile("s_waitcnt vmcnt(3)" ::: "memory");
      else                         asm volatile("s_waitcnt vmcnt(4)" ::: "memory");
    } else {
      asm volatile("s_waitcnt vmcnt(0)" ::: "memory");
    }
    __builtin_amdgcn_s_barrier();
    __builtin_amdgcn_sched_barrier(0);
    if (ti + 2 < nt) stage((ti + 2) << 5, lds + ps * BUFSZ);
    __builtin_amdgcn_s_setprio(1);
    compute(lds + cs * BUFSZ);
    __builtin_amdgcn_s_setprio(0);
    cs = (cs == 2) ? 0 : cs + 1;
    ps = (ps == 2) ? 0 : ps + 1;
  }

  const int cr = fh * 4;
  const float bscal = (bias_mode == 2) ? bias[0] : 0.f;
#pragma unroll
  for (int m = 0; m < MFR; ++m) {
#pragma unroll
    for (int n = 0; n < NFR; ++n) {
      const int col = tn + wc * WCC + n * 16 + fr;
      const float bv = (bias_mode == 1) ? bias[col] : bscal;
#pragma unroll
      for (int j = 0; j < 4; ++j) {
        const int row = tm + wr * WR + m * 16 + cr + j;
        float v = acc[m][n][j] + bv;
        if (relu) v = fmaxf(v, 0.f);
        if (out_bf16)
          ((ushort*)C)[(size_t)row * ldc + col] = f2bf(v);
        else
          ((float*)C)[(size_t)row * ldc + col] = v;
      }
    }
  }
}

// Prep work unit u (0..7299); all threads of a block share u.
static __device__ void prep_unit(
    int u, int tid, float* tlds,
    const float* __restrict__ w1h, const float* __restrict__ b1h,
    const float* __restrict__ w1d, const float* __restrict__ b1d,
    const float* __restrict__ w2h, const float* __restrict__ b2h,
    const float* __restrict__ w2d, const float* __restrict__ b2d,
    const float* __restrict__ Wb, const float4* __restrict__ hs,
    ushort* __restrict__ W1, ushort* __restrict__ WbT,
    ushort* __restrict__ w2hT, ushort* __restrict__ W2,
    float* __restrict__ b1c, ushort* __restrict__ hs_bf) {
  if (u < 4096) {
    int idx = u * 256 + tid;
    int n = idx >> 10, k = idx & 1023;
    float v = 0.f;
    if (n < ARC) v = w1h[(size_t)n * HIDDEN + k];
    else if (n >= AP && n < AP + ARC) v = w1d[(size_t)(n - AP) * HIDDEN + k];
    W1[idx] = f2bf(v);
  } else if (u < 5120) {
    int idx = (u - 4096) * 256 + tid;
    int n = idx >> 9, k = idx & 511;
    float v = 0.f;
    if (n < ARC) {
      if (k < ARC) v = w2d[(size_t)n * ARC + k];
      else if (k == 511) v = b2d[n];
    }
    W2[idx] = f2bf(v);
  } else if (u < 5184) {
    const int tile = u - 5120;
    const int ta = tile >> 3, tj = tile & 7;
#pragma unroll
    for (int i = 0; i < 16; ++i) {
      int e = i * 256 + tid;
      int jl = e >> 6, al = e & 63;
      int j = tj * 64 + jl, a = ta * 64 + al;
      tlds[jl * 65 + al] = (j < ARC && a < ARC) ? Wb[(size_t)j * ARC + a] : 0.f;
    }
    __syncthreads();
#pragma unroll
    for (int i = 0; i < 16; ++i) {
      int e = i * 256 + tid;
      int al = e >> 6, jl = e & 63;
      WbT[(size_t)(ta * 64 + al) * AP + tj * 64 + jl] = f2bf(tlds[jl * 65 + al]);
    }
    __syncthreads();  // tlds safe for next unit
  } else if (u < 5248) {
    const int tile = u - 5184;
    const int tk = tile >> 3, tj = tile & 7;
#pragma unroll
    for (int i = 0; i < 16; ++i) {
      int e = i * 256 + tid;
      int jl = e >> 6, kl = e & 63;
      int j = tj * 64 + jl, k = tk * 64 + kl;
      tlds[jl * 65 + kl] = (j < ARC && k < ARC) ? w2h[(size_t)j * ARC + k] : 0.f;
    }
    __syncthreads();
#pragma unroll
    for (int i = 0; i < 16; ++i) {
      int e = i * 256 + tid;
      int kl = e >> 6, jl = e & 63;
      int k = tk * 64 + kl, j = tj * 64 + jl;
      float v = tlds[jl * 65 + kl];
      if (k == 511) v = (j < ARC) ? b2h[j] : 0.f;
      w2hT[(size_t)k * AP + j] = f2bf(v);
    }
    __syncthreads();
  } else if (u < 5252) {
    int i = (u - 5248) * 256 + tid;
    float v = 0.f;
    if (i < ARC) v = b1h[i];
    else if (i == 511 || i == 1023) v = 1.f;
    else if (i >= AP && i < AP + ARC) v = b1d[i - AP];
    b1c[i] = v;
  } else {
    const int n4 = ROWS * HIDDEN / 4;
    for (int i = (u - 5252) * 256 + tid; i < n4; i += 2048 * 256) {
      float4 v = hs[i];
      ushort4 o;
      o.x = f2bf(v.x); o.y = f2bf(v.y); o.z = f2bf(v.z); o.w = f2bf(v.w);
      *(ushort4*)(hs_bf + (size_t)i * 4) = o;
    }
  }
}

__global__ __launch_bounds__(256)
void k_fused(const float* __restrict__ w1h, const float* __restrict__ b1h,
             const float* __restrict__ w2h, const float* __restrict__ b2h,
             const float* __restrict__ w1d, const float* __restrict__ b1d,
             const float* __restrict__ w2d, const float* __restrict__ b2d,
             const float* __restrict__ Wb, const float* __restrict__ bb,
             const float4* __restrict__ hs,
             ushort* __restrict__ hs_bf, ushort* __restrict__ W1,
             ushort* __restrict__ WbT, ushort* __restrict__ w2hT,
             ushort* __restrict__ MT, ushort* __restrict__ W2,
             ushort* __restrict__ t1, ushort* __restrict__ hw,
             float* __restrict__ b1c, float* __restrict__ out,
             unsigned* __restrict__ barcnt) {
  __shared__ ushort lds[3 * (128 + 128) * 32];  // 48 KB
  const int b = blockIdx.x;   // 0..511
  const int tid = threadIdx.x;

  // ---- phase 0: prep (7300 units, block-strided) ----
  for (int u = b; u < 7300; u += NB)
    prep_unit(u, tid, (float*)lds, w1h, b1h, w1d, b1d, w2h, b2h, w2d, b2d,
              Wb, hs, W1, WbT, w2hT, W2, b1c, hs_bf);
  gsync(barcnt, NB);

  // ---- phase 1: GEMM1 (512 x 128x128 tiles) + MT (64 x 64x64 tiles) ----
  {
    const int f2 = (b & 7) * 64 + (b >> 3);  // XCD-bijective
    const int by = f2 >> 3, bx = f2 & 7;     // 64 x 8 tiles
    gemm_body<128, 128>(hs_bf, W1, b1c, 1, t1, 1, 1,
                        HIDDEN, HIDDEN, 1024, HIDDEN, by * 128, bx * 128, lds);
    if (b < 64) {
      // MT[a][k] = sum_j WbT[a][j] * w2hT[k][j]   [512x512], K=512
      gemm_body<64, 64>(WbT, w2hT, nullptr, 0, MT, 1, 0,
                        AP, AP, AP, AP, (b >> 3) * 64, (b & 7) * 64, lds);
    }
  }
  gsync(barcnt, 2 * NB);

  // ---- phase 2: GEMM2 (z=0 headW = t1h @ MT^T ; z=1 dep = t1d @ W2^T) ----
  {
    const int f2 = (b & 7) * 64 + (b >> 3);
    const int z = f2 >> 8;                   // 0..1
    const int rm = f2 & 255;
    const int by = rm >> 2, bx = rm & 3;     // 64 x 4 tiles of 128x128
    const ushort* Az = t1 + (size_t)z * AP;
    const ushort* Bz = z ? W2 : MT;
    ushort* Cz = hw + (size_t)z * ROWS * AP;
    gemm_body<128, 128>(Az, Bz, nullptr, 0, Cz, 1, 0,
                        1024, AP, AP, AP, by * 128, bx * 128, lds);
  }
  gsync(barcnt, 3 * NB);

  // ---- phase 3: GEMM3 (scores_b = headW_b @ dep_b^T + bb -> f32) ----
  {
    const int f2 = (b & 7) * 64 + (b >> 3);
    const int z = f2 >> 5;                   // 0..15
    const int tt = f2 & 31;
    const int by = tt >> 3, bx = tt & 7;     // 4 x 8 tiles of 128x64
    const ushort* Az = hw + (size_t)z * 512 * AP;
    const ushort* Bz = hw + (size_t)ROWS * AP + (size_t)z * 512 * AP;
    float* Cz = out + (size_t)z * 512 * 512;
    gemm_body<128, 64>(Az, Bz, bb, 2, Cz, 0, 0,
                       AP, AP, 512, AP, by * 128, bx * 64, lds);
  }
}

extern "C" void kernel_launch(void* const* d_in, const int* in_sizes, int n_in,
                              void* d_out, int out_size, void* d_ws, size_t ws_size,
                              hipStream_t stream) {
  const float* hs  = (const float*)d_in[0];
  const float* w1h = (const float*)d_in[1];
  const float* b1h = (const float*)d_in[2];
  const float* w2h = (const float*)d_in[3];
  const float* b2h = (const float*)d_in[4];
  const float* w1d = (const float*)d_in[5];
  const float* b1d = (const float*)d_in[6];
  const float* w2d = (const float*)d_in[7];
  const float* b2d = (const float*)d_in[8];
  const float* Wb  = (const float*)d_in[9];
  const float* bb  = (const float*)d_in[10];

  char* ws = (char*)d_ws;
  ushort*   hs_bf = (ushort*)(ws + 0);          // 16 MB
  ushort*   W1    = (ushort*)(ws + 16777216);   // 2 MB
  ushort*   WbT   = (ushort*)(ws + 18874368);   // 512 KB
  ushort*   w2hT  = (ushort*)(ws + 19398656);   // 512 KB
  ushort*   MT    = (ushort*)(ws + 19922944);   // 512 KB
  ushort*   W2    = (ushort*)(ws + 20447232);   // 512 KB
  ushort*   t1    = (ushort*)(ws + 20971520);   // 16 MB
  ushort*   hw    = (ushort*)(ws + 37748736);   // 16 MB (headW | dep)
  float*    b1c   = (float*)(ws + 54525952);    // 4 KB
  unsigned* bar   = (unsigned*)(ws + 54530048); // 4 B barrier counter
  float*    out   = (float*)d_out;

  hipMemsetAsync(bar, 0, 4, stream);
  k_fused<<<NB, 256, 0, stream>>>(w1h, b1h, w2h, b2h, w1d, b1d, w2d, b2d,
                                  Wb, bb, (const float4*)hs,
                                  hs_bf, W1, WbT, w2hT, MT, W2, t1, hw,
                                  b1c, out, bar);
}